// Round 1
// baseline (1161.418 us; speedup 1.0000x reference)
//
#include <hip/hip_runtime.h>

#define HW 4096

// ---------------- kernel A: per-(q,r,ns,c) instance-norm stats ----------------
__global__ __launch_bounds__(256) void k_stats(const float* __restrict__ corr,
                                               float* __restrict__ scl,
                                               float* __restrict__ shf) {
  int g = blockIdx.x;  // 0..9215  linear over [q][r][ns][c]
  const float4* p = (const float4*)(corr + (size_t)g * HW);
  int t = threadIdx.x;
  float s = 0.f, s2 = 0.f;
#pragma unroll
  for (int i = 0; i < 4; i++) {
    float4 v = p[t + i * 256];
    s += v.x + v.y + v.z + v.w;
    s2 += v.x * v.x + v.y * v.y + v.z * v.z + v.w * v.w;
  }
#pragma unroll
  for (int o = 32; o > 0; o >>= 1) {
    s += __shfl_down(s, o, 64);
    s2 += __shfl_down(s2, o, 64);
  }
  __shared__ float ls[4], ls2[4];
  int wid = t >> 6;
  if ((t & 63) == 0) { ls[wid] = s; ls2[wid] = s2; }
  __syncthreads();
  if (t == 0) {
    float S = ls[0] + ls[1] + ls[2] + ls[3];
    float S2 = ls2[0] + ls2[1] + ls2[2] + ls2[3];
    float m = S * (1.f / HW);
    float var = S2 * (1.f / HW) - m * m;
    float r = rsqrtf(var + 1e-5f);
    scl[g] = r;
    shf[g] = -m * r;
  }
}

// ---------------- kernel B: ref_score = mean_c corr_n -> rs[(q*32+r)*4+ns][px]
__global__ __launch_bounds__(256) void k_refscore(const float* __restrict__ corr,
                                                  const float* __restrict__ scl,
                                                  const float* __restrict__ shf,
                                                  float* __restrict__ rs) {
  int b = blockIdx.x;     // 2048
  int grp = b >> 2;       // 0..511
  int i4 = (b & 3) * 256 + threadIdx.x;  // float4 index 0..1023
  const float* base = corr + (size_t)grp * 18 * HW;
  float4 acc = make_float4(0.f, 0.f, 0.f, 0.f);
  float sh = 0.f;
#pragma unroll
  for (int c = 0; c < 18; c++) {
    float s = scl[grp * 18 + c];
    sh += shf[grp * 18 + c];
    float4 v = ((const float4*)(base + c * HW))[i4];
    acc.x += v.x * s; acc.y += v.y * s; acc.z += v.z * s; acc.w += v.w * s;
  }
  const float inv = 1.f / 18.f;
  float4 o;
  o.x = (acc.x + sh) * inv; o.y = (acc.y + sh) * inv;
  o.z = (acc.z + sh) * inv; o.w = (acc.w + sh) * inv;
  ((float4*)(rs + (size_t)grp * HW))[i4] = o;
}

// ---------------- kernel C: top-4 of 32 (jax tie semantics) ----------------
__global__ __launch_bounds__(256) void k_topk(const float* __restrict__ rs,
                                              int* __restrict__ topidx) {
  int idx = blockIdx.x * 256 + threadIdx.x;  // 65536 = (q*4+ns)*4096+px
  int px = idx & 4095;
  int ns = (idx >> 12) & 3;
  int q = idx >> 14;
  float v[32];
#pragma unroll
  for (int r = 0; r < 32; r++) v[r] = rs[((q * 32 + r) * 4 + ns) * HW + px];
  unsigned mask = 0;
  int sel[4];
#pragma unroll
  for (int k = 0; k < 4; k++) {
    float best = -3.4e38f;
    int bi = 0;
#pragma unroll
    for (int r = 0; r < 32; r++) {
      bool take = (!(mask & (1u << r))) && (v[r] > best);
      best = take ? v[r] : best;
      bi = take ? r : bi;
    }
    sel[k] = bi;
    mask |= (1u << bi);
  }
  ((int4*)topidx)[idx] = make_int4(sel[0], sel[1], sel[2], sel[3]);
}

// -------- kernel D: gather+norm, both 2-layer 1x1x1 MLPs, NS-max -> xs, xc ----
__global__ __launch_bounds__(128) void k_mlp(
    const float* __restrict__ corr, const float* __restrict__ scl,
    const float* __restrict__ shf, const int* __restrict__ topidx,
    const float* __restrict__ w1s, const float* __restrict__ b1s,
    const float* __restrict__ w2s, const float* __restrict__ b2s,
    const float* __restrict__ w1c, const float* __restrict__ b1c,
    const float* __restrict__ w2c, const float* __restrict__ b2c,
    float* __restrict__ xs, float* __restrict__ xc) {
  __shared__ float hs[64 * 128];   // 32 KB: h1[c] per thread
  __shared__ float rbuf[8 * 128];  // 4 KB: layer-2 outputs for ns-max
  int b = blockIdx.x;  // 512
  int q = b >> 7;
  int pxbase = (b & 127) * 32;
  int tid = threadIdx.x;
  int ns = tid >> 5;
  int lane = tid & 31;
  int px = pxbase + lane;

  int4 ti = ((const int4*)topidx)[(q * 4 + ns) * HW + px];
  int rk[4] = {ti.x, ti.y, ti.z, ti.w};
  float v[72];
#pragma unroll
  for (int k = 0; k < 4; k++) {
    int g = ((q * 32 + rk[k]) * 4 + ns) * 18;
    const float* cp = corr + (size_t)g * HW + px;
#pragma unroll
    for (int c = 0; c < 18; c++) v[k * 18 + c] = cp[c * HW] * scl[g + c] + shf[g + c];
  }
  float xsc[12];
#pragma unroll
  for (int k = 0; k < 4; k++)
#pragma unroll
    for (int l = 0; l < 3; l++) {
      float s = 0.f;
#pragma unroll
      for (int j = 0; j < 6; j++) s += v[k * 18 + l * 6 + j];
      xsc[k * 3 + l] = s * (1.f / 6.f);
    }
  // scale path layer 1
  for (int o = 0; o < 64; o++) {
    float t = b1s[o];
#pragma unroll
    for (int c = 0; c < 72; c++) t += w1s[o * 72 + c] * v[c];
    hs[o * 128 + tid] = fmaxf(t, 0.f);
  }
  __syncthreads();
  // scale path layer 2 + ns-max
  for (int og = 0; og < 8; og++) {
    float t[8];
#pragma unroll
    for (int j = 0; j < 8; j++) t[j] = b2s[og * 8 + j];
#pragma unroll 8
    for (int c = 0; c < 64; c++) {
      float x = hs[c * 128 + tid];
#pragma unroll
      for (int j = 0; j < 8; j++) t[j] += w2s[(og * 8 + j) * 64 + c] * x;
    }
#pragma unroll
    for (int j = 0; j < 8; j++) rbuf[j * 128 + tid] = t[j];
    __syncthreads();
#pragma unroll
    for (int pass = 0; pass < 2; pass++) {
      int j2 = (tid >> 5) + pass * 4;
      float m = rbuf[j2 * 128 + lane];
#pragma unroll
      for (int n2 = 1; n2 < 4; n2++) m = fmaxf(m, rbuf[j2 * 128 + n2 * 32 + lane]);
      xs[(q * 64 + og * 8 + j2) * HW + pxbase + lane] = m;
    }
    __syncthreads();
  }
  // score path layer 1 (overwrites hs)
  for (int o = 0; o < 64; o++) {
    float t = b1c[o];
#pragma unroll
    for (int c = 0; c < 12; c++) t += w1c[o * 12 + c] * xsc[c];
    hs[o * 128 + tid] = fmaxf(t, 0.f);
  }
  __syncthreads();
  // score path layer 2 + ns-max
  for (int og = 0; og < 8; og++) {
    float t[8];
#pragma unroll
    for (int j = 0; j < 8; j++) t[j] = b2c[og * 8 + j];
#pragma unroll 8
    for (int c = 0; c < 64; c++) {
      float x = hs[c * 128 + tid];
#pragma unroll
      for (int j = 0; j < 8; j++) t[j] += w2c[(og * 8 + j) * 64 + c] * x;
    }
#pragma unroll
    for (int j = 0; j < 8; j++) rbuf[j * 128 + tid] = t[j];
    __syncthreads();
#pragma unroll
    for (int pass = 0; pass < 2; pass++) {
      int j2 = (tid >> 5) + pass * 4;
      float m = rbuf[j2 * 128 + lane];
#pragma unroll
      for (int n2 = 1; n2 < 4; n2++) m = fmaxf(m, rbuf[j2 * 128 + n2 * 32 + lane]);
      xc[(q * 64 + og * 8 + j2) * HW + pxbase + lane] = m;
    }
    __syncthreads();
  }
}

// ---------------- 3x3 SAME conv, 64 in-ch, LDS-tiled ----------------
template <int OC, int OCPB, bool RELU>
__global__ __launch_bounds__(256) void k_conv3(const float* __restrict__ in,
                                               const float* __restrict__ wt,
                                               const float* __restrict__ bias,
                                               float* __restrict__ out) {
  constexpr int NOG = OC / OCPB;
  __shared__ float lds[16 * 6 * 66];  // 25.3 KB: 16 ic x 6 rows x (64+2 pad) cols
  int b = blockIdx.x;                 // q*16*NOG
  int og = b % NOG;
  int rt = (b / NOG) & 15;
  int q = b / (NOG * 16);
  int t = threadIdx.x;
  int w = t & 63, wr = t >> 6;  // output col, row-in-tile (4 rows/tile)
  float acc[OCPB];
#pragma unroll
  for (int o = 0; o < OCPB; o++) acc[o] = 0.f;
  const float* inq = in + (size_t)q * 64 * HW;
  for (int icc = 0; icc < 4; icc++) {
    __syncthreads();
    for (int e = t; e < 16 * 6 * 66; e += 256) {
      int cc = e % 66;
      int tmp = e / 66;
      int r = tmp % 6, ch = tmp / 6;
      int col = cc - 1;
      int grow = rt * 4 + r - 1;
      float val = 0.f;
      if (col >= 0 && col < 64 && grow >= 0 && grow < 64)
        val = inq[(icc * 16 + ch) * HW + grow * 64 + col];
      lds[e] = val;
    }
    __syncthreads();
#pragma unroll 4
    for (int ic = 0; ic < 16; ic++) {
      float x00 = lds[(ic * 6 + wr) * 66 + w];
      float x01 = lds[(ic * 6 + wr) * 66 + w + 1];
      float x02 = lds[(ic * 6 + wr) * 66 + w + 2];
      float x10 = lds[(ic * 6 + wr + 1) * 66 + w];
      float x11 = lds[(ic * 6 + wr + 1) * 66 + w + 1];
      float x12 = lds[(ic * 6 + wr + 1) * 66 + w + 2];
      float x20 = lds[(ic * 6 + wr + 2) * 66 + w];
      float x21 = lds[(ic * 6 + wr + 2) * 66 + w + 1];
      float x22 = lds[(ic * 6 + wr + 2) * 66 + w + 2];
      const float* wb = wt + (size_t)og * OCPB * 576 + (icc * 16 + ic) * 9;
#pragma unroll
      for (int o = 0; o < OCPB; o++) {
        const float* wp = wb + o * 576;
        acc[o] += wp[0] * x00 + wp[1] * x01 + wp[2] * x02 + wp[3] * x10 +
                  wp[4] * x11 + wp[5] * x12 + wp[6] * x20 + wp[7] * x21 +
                  wp[8] * x22;
      }
    }
  }
  int orow = rt * 4 + wr;
#pragma unroll
  for (int o = 0; o < OCPB; o++) {
    float r = acc[o] + bias[og * OCPB + o];
    if (RELU) r = fmaxf(r, 0.f);
    out[((size_t)q * OC + og * OCPB + o) * HW + orow * 64 + w] = r;
  }
}

// ---------------- final: argmax + pos/scl ----------------
__global__ __launch_bounds__(256) void k_final(const float* __restrict__ scores,
                                               const float* __restrict__ scales,
                                               const float* __restrict__ offsets,
                                               float* __restrict__ pos,
                                               float* __restrict__ sclo) {
  int q = blockIdx.x, t = threadIdx.x;
  float best = -3.4e38f;
  int bi = 1 << 30;
  for (int i = t; i < HW; i += 256) {
    float v = scores[q * HW + i];
    if (v > best) { best = v; bi = i; }
  }
  __shared__ float bv[256];
  __shared__ int bix[256];
  bv[t] = best;
  bix[t] = bi;
  __syncthreads();
  for (int s = 128; s > 0; s >>= 1) {
    if (t < s) {
      if (bv[t + s] > bv[t] || (bv[t + s] == bv[t] && bix[t + s] < bix[t])) {
        bv[t] = bv[t + s];
        bix[t] = bix[t + s];
      }
    }
    __syncthreads();
  }
  if (t == 0) {
    int sid = bix[0];
    int sy = sid >> 6, sx = sid & 63;
    float o0 = offsets[(q * 2 + 0) * HW + sid];
    float o1 = offsets[(q * 2 + 1) * HW + sid];
    pos[q * 2 + 0] = ((float)sx + o0 + 0.5f) * 8.f - 0.5f;
    pos[q * 2 + 1] = ((float)sy + o1 + 0.5f) * 8.f - 0.5f;
    sclo[q] = exp2f(scales[q * HW + sid]);
  }
}

extern "C" void kernel_launch(void* const* d_in, const int* in_sizes, int n_in,
                              void* d_out, int out_size, void* d_ws, size_t ws_size,
                              hipStream_t stream) {
  const float* corr = (const float*)d_in[0];
  const float* w1s = (const float*)d_in[1];
  const float* b1s = (const float*)d_in[2];
  const float* w2s = (const float*)d_in[3];
  const float* b2s = (const float*)d_in[4];
  const float* w1c = (const float*)d_in[5];
  const float* b1c = (const float*)d_in[6];
  const float* w2c = (const float*)d_in[7];
  const float* b2c = (const float*)d_in[8];

  float* out = (float*)d_out;
  float* pos = out;                   // (4,2)
  float* sclo = out + 8;              // (4,)
  float* scores = out + 12;           // (4,1,64,64)
  float* scales = out + 12 + 16384;   // (4,1,64,64)
  float* offsets = out + 12 + 32768;  // (4,2,64,64)

  char* ws = (char*)d_ws;
  float* st_scl = (float*)(ws + 0);         // 9216 f
  float* st_shf = (float*)(ws + 36864);     // 9216 f
  int* topidx = (int*)(ws + 73728);         // 65536 int4 = 1 MB
  float* rs = (float*)(ws + 1122304);       // 8.39 MB
  float* xs = (float*)(ws + 9510912);       // 4.19 MB
  float* xc = (float*)(ws + 13705216);      // 4.19 MB
  float* t1 = (float*)(ws + 17899520);      // 4.19 MB
  float* t2 = (float*)(ws + 22093824);      // 4.19 MB (total 26.3 MB)

  k_stats<<<9216, 256, 0, stream>>>(corr, st_scl, st_shf);
  k_refscore<<<2048, 256, 0, stream>>>(corr, st_scl, st_shf, rs);
  k_topk<<<256, 256, 0, stream>>>(rs, topidx);
  k_mlp<<<512, 128, 0, stream>>>(corr, st_scl, st_shf, topidx, w1s, b1s, w2s,
                                 b2s, w1c, b1c, w2c, b2c, xs, xc);
  // scale head -> scales
  k_conv3<64, 8, true><<<512, 256, 0, stream>>>(xs, (const float*)d_in[9], (const float*)d_in[10], t1);
  k_conv3<64, 8, true><<<512, 256, 0, stream>>>(t1, (const float*)d_in[11], (const float*)d_in[12], t2);
  k_conv3<1, 1, false><<<64, 256, 0, stream>>>(t2, (const float*)d_in[13], (const float*)d_in[14], scales);
  // offset head -> offsets
  k_conv3<64, 8, true><<<512, 256, 0, stream>>>(xc, (const float*)d_in[15], (const float*)d_in[16], t1);
  k_conv3<64, 8, true><<<512, 256, 0, stream>>>(t1, (const float*)d_in[17], (const float*)d_in[18], t2);
  k_conv3<2, 2, false><<<64, 256, 0, stream>>>(t2, (const float*)d_in[19], (const float*)d_in[20], offsets);
  // score head -> scores
  k_conv3<64, 8, true><<<512, 256, 0, stream>>>(xc, (const float*)d_in[21], (const float*)d_in[22], t1);
  k_conv3<64, 8, true><<<512, 256, 0, stream>>>(t1, (const float*)d_in[23], (const float*)d_in[24], t2);
  k_conv3<1, 1, false><<<64, 256, 0, stream>>>(t2, (const float*)d_in[25], (const float*)d_in[26], scores);

  k_final<<<4, 256, 0, stream>>>(scores, scales, offsets, pos, sclo);
}

// Round 2
// 1074.981 us; speedup vs baseline: 1.0804x; 1.0804x over previous
//
#include <hip/hip_runtime.h>

#define HW 4096

// ---------------- kernel A: per-(q,r,ns,c) instance-norm stats ----------------
__global__ __launch_bounds__(256) void k_stats(const float* __restrict__ corr,
                                               float* __restrict__ scl,
                                               float* __restrict__ shf) {
  int g = blockIdx.x;  // 0..9215  linear over [q][r][ns][c]
  const float4* p = (const float4*)(corr + (size_t)g * HW);
  int t = threadIdx.x;
  float s = 0.f, s2 = 0.f;
#pragma unroll
  for (int i = 0; i < 4; i++) {
    float4 v = p[t + i * 256];
    s += v.x + v.y + v.z + v.w;
    s2 += v.x * v.x + v.y * v.y + v.z * v.z + v.w * v.w;
  }
#pragma unroll
  for (int o = 32; o > 0; o >>= 1) {
    s += __shfl_down(s, o, 64);
    s2 += __shfl_down(s2, o, 64);
  }
  __shared__ float ls[4], ls2[4];
  int wid = t >> 6;
  if ((t & 63) == 0) { ls[wid] = s; ls2[wid] = s2; }
  __syncthreads();
  if (t == 0) {
    float S = ls[0] + ls[1] + ls[2] + ls[3];
    float S2 = ls2[0] + ls2[1] + ls2[2] + ls2[3];
    float m = S * (1.f / HW);
    float var = S2 * (1.f / HW) - m * m;
    float r = rsqrtf(var + 1e-5f);
    scl[g] = r;
    shf[g] = -m * r;
  }
}

// ---------------- kernel B: ref_score = mean_c corr_n -> rs[(q*32+r)*4+ns][px]
__global__ __launch_bounds__(256) void k_refscore(const float* __restrict__ corr,
                                                  const float* __restrict__ scl,
                                                  const float* __restrict__ shf,
                                                  float* __restrict__ rs) {
  int b = blockIdx.x;     // 2048
  int grp = b >> 2;       // 0..511
  int i4 = (b & 3) * 256 + threadIdx.x;  // float4 index 0..1023
  const float* base = corr + (size_t)grp * 18 * HW;
  float4 acc = make_float4(0.f, 0.f, 0.f, 0.f);
  float sh = 0.f;
#pragma unroll
  for (int c = 0; c < 18; c++) {
    float s = scl[grp * 18 + c];
    sh += shf[grp * 18 + c];
    float4 v = ((const float4*)(base + c * HW))[i4];
    acc.x += v.x * s; acc.y += v.y * s; acc.z += v.z * s; acc.w += v.w * s;
  }
  const float inv = 1.f / 18.f;
  float4 o;
  o.x = (acc.x + sh) * inv; o.y = (acc.y + sh) * inv;
  o.z = (acc.z + sh) * inv; o.w = (acc.w + sh) * inv;
  ((float4*)(rs + (size_t)grp * HW))[i4] = o;
}

// ---------------- kernel C: top-4 of 32 (jax tie semantics) ----------------
__global__ __launch_bounds__(256) void k_topk(const float* __restrict__ rs,
                                              int* __restrict__ topidx) {
  int idx = blockIdx.x * 256 + threadIdx.x;  // 65536 = (q*4+ns)*4096+px
  int px = idx & 4095;
  int ns = (idx >> 12) & 3;
  int q = idx >> 14;
  float v[32];
#pragma unroll
  for (int r = 0; r < 32; r++) v[r] = rs[((q * 32 + r) * 4 + ns) * HW + px];
  unsigned mask = 0;
  int sel[4];
#pragma unroll
  for (int k = 0; k < 4; k++) {
    float best = -3.4e38f;
    int bi = 0;
#pragma unroll
    for (int r = 0; r < 32; r++) {
      bool take = (!(mask & (1u << r))) && (v[r] > best);
      best = take ? v[r] : best;
      bi = take ? r : bi;
    }
    sel[k] = bi;
    mask |= (1u << bi);
  }
  ((int4*)topidx)[idx] = make_int4(sel[0], sel[1], sel[2], sel[3]);
}

// -------- kernel D: STREAMING select + norm, both MLPs, NS-max -> xs, xc ----
// Block = 4 ns x 32 px (128 thr). Instead of a random gather (which fetched
// ~the whole corr anyway at 1 TB/s), stream ALL 32 r x 18 c rows coalesced
// and cndmask-select raw values where r matches top-4; normalize lazily.
__global__ __launch_bounds__(128) void k_mlp(
    const float* __restrict__ corr, const float* __restrict__ scl,
    const float* __restrict__ shf, const int* __restrict__ topidx,
    const float* __restrict__ w1s, const float* __restrict__ b1s,
    const float* __restrict__ w2s, const float* __restrict__ b2s,
    const float* __restrict__ w1c, const float* __restrict__ b1c,
    const float* __restrict__ w2c, const float* __restrict__ b2c,
    float* __restrict__ xs, float* __restrict__ xc) {
  __shared__ float hs[64 * 128];    // 32 KB: h1[c] per thread
  __shared__ float rbuf[8 * 128];   // 4 KB: layer-2 outputs for ns-max
  __shared__ float s_scl[32 * 4 * 18];  // 9.2 KB: this q's scl slice
  __shared__ float s_shf[32 * 4 * 18];  // 9.2 KB
  int b = blockIdx.x;  // 512
  int q = b >> 7;
  int pxbase = (b & 127) * 32;
  int tid = threadIdx.x;
  int ns = tid >> 5;
  int lane = tid & 31;
  int px = pxbase + lane;

  for (int j = tid; j < 2304; j += 128) {
    s_scl[j] = scl[q * 2304 + j];
    s_shf[j] = shf[q * 2304 + j];
  }
  int4 ti = ((const int4*)topidx)[(q * 4 + ns) * HW + px];
  int rk0 = ti.x, rk1 = ti.y, rk2 = ti.z, rk3 = ti.w;
  __syncthreads();

  float v[72];
  // coalesced stream over all (r,c) rows; per-lane select of raw values
#pragma unroll 2
  for (int r = 0; r < 32; r++) {
    const float* cp = corr + (size_t)(((q * 32 + r) * 4 + ns) * 18) * HW + px;
    bool m0 = (rk0 == r), m1 = (rk1 == r), m2 = (rk2 == r), m3 = (rk3 == r);
#pragma unroll
    for (int c = 0; c < 18; c++) {
      float x = cp[c * HW];
      if (m0) v[0 * 18 + c] = x;
      if (m1) v[1 * 18 + c] = x;
      if (m2) v[2 * 18 + c] = x;
      if (m3) v[3 * 18 + c] = x;
    }
  }
  // lazy normalization (144 LDS lookups, per-lane addressed)
  int gk[4] = {(rk0 * 4 + ns) * 18, (rk1 * 4 + ns) * 18, (rk2 * 4 + ns) * 18,
               (rk3 * 4 + ns) * 18};
#pragma unroll
  for (int k = 0; k < 4; k++)
#pragma unroll
    for (int c = 0; c < 18; c++)
      v[k * 18 + c] = v[k * 18 + c] * s_scl[gk[k] + c] + s_shf[gk[k] + c];

  float xsc[12];
#pragma unroll
  for (int k = 0; k < 4; k++)
#pragma unroll
    for (int l = 0; l < 3; l++) {
      float s = 0.f;
#pragma unroll
      for (int j = 0; j < 6; j++) s += v[k * 18 + l * 6 + j];
      xsc[k * 3 + l] = s * (1.f / 6.f);
    }
  // scale path layer 1
  for (int o = 0; o < 64; o++) {
    float t = b1s[o];
#pragma unroll
    for (int c = 0; c < 72; c++) t += w1s[o * 72 + c] * v[c];
    hs[o * 128 + tid] = fmaxf(t, 0.f);
  }
  __syncthreads();
  // scale path layer 2 + ns-max
  for (int og = 0; og < 8; og++) {
    float t[8];
#pragma unroll
    for (int j = 0; j < 8; j++) t[j] = b2s[og * 8 + j];
#pragma unroll 8
    for (int c = 0; c < 64; c++) {
      float x = hs[c * 128 + tid];
#pragma unroll
      for (int j = 0; j < 8; j++) t[j] += w2s[(og * 8 + j) * 64 + c] * x;
    }
#pragma unroll
    for (int j = 0; j < 8; j++) rbuf[j * 128 + tid] = t[j];
    __syncthreads();
#pragma unroll
    for (int pass = 0; pass < 2; pass++) {
      int j2 = (tid >> 5) + pass * 4;
      float m = rbuf[j2 * 128 + lane];
#pragma unroll
      for (int n2 = 1; n2 < 4; n2++) m = fmaxf(m, rbuf[j2 * 128 + n2 * 32 + lane]);
      xs[(q * 64 + og * 8 + j2) * HW + pxbase + lane] = m;
    }
    __syncthreads();
  }
  // score path layer 1 (overwrites hs)
  for (int o = 0; o < 64; o++) {
    float t = b1c[o];
#pragma unroll
    for (int c = 0; c < 12; c++) t += w1c[o * 12 + c] * xsc[c];
    hs[o * 128 + tid] = fmaxf(t, 0.f);
  }
  __syncthreads();
  // score path layer 2 + ns-max
  for (int og = 0; og < 8; og++) {
    float t[8];
#pragma unroll
    for (int j = 0; j < 8; j++) t[j] = b2c[og * 8 + j];
#pragma unroll 8
    for (int c = 0; c < 64; c++) {
      float x = hs[c * 128 + tid];
#pragma unroll
      for (int j = 0; j < 8; j++) t[j] += w2c[(og * 8 + j) * 64 + c] * x;
    }
#pragma unroll
    for (int j = 0; j < 8; j++) rbuf[j * 128 + tid] = t[j];
    __syncthreads();
#pragma unroll
    for (int pass = 0; pass < 2; pass++) {
      int j2 = (tid >> 5) + pass * 4;
      float m = rbuf[j2 * 128 + lane];
#pragma unroll
      for (int n2 = 1; n2 < 4; n2++) m = fmaxf(m, rbuf[j2 * 128 + n2 * 32 + lane]);
      xc[(q * 64 + og * 8 + j2) * HW + pxbase + lane] = m;
    }
    __syncthreads();
  }
}

// ---------------- big 3x3 SAME conv, 64 ic, 64 oc: 2-row tiles, pow2 fill ----
template <bool RELU>
__global__ __launch_bounds__(256) void k_conv64(const float* __restrict__ in,
                                                const float* __restrict__ wt,
                                                const float* __restrict__ bias,
                                                float* __restrict__ out) {
  __shared__ float lds[64 * 66];  // 16.9 KB: 16 ic x 4 rows x (1+64+1)
  int b = blockIdx.x;             // 1024 = q*32rt*8og
  int og = b & 7;
  int rt = (b >> 3) & 31;
  int q = b >> 8;
  int t = threadIdx.x;
  int w = t & 63;
  int wr = t >> 6;       // 0..3
  int orow2 = wr & 1;    // which of the 2 output rows
  int oh = wr >> 1;      // which 4-oc half
  float acc[4] = {0.f, 0.f, 0.f, 0.f};
  if (t < 64) { lds[t * 66] = 0.f; lds[t * 66 + 65] = 0.f; }
  const float* inq = in + (size_t)q * 64 * HW;
  for (int icc = 0; icc < 4; icc++) {
    __syncthreads();
#pragma unroll
    for (int p = 0; p < 16; p++) {
      int row = wr + p * 4;       // 0..63
      int ch = row >> 2;          // ic in chunk
      int r = row & 3;
      int grow = rt * 2 + r - 1;  // input image row
      float val = 0.f;
      if (grow >= 0 && grow < 64)
        val = inq[(size_t)(icc * 16 + ch) * HW + grow * 64 + w];
      lds[row * 66 + 1 + w] = val;
    }
    __syncthreads();
#pragma unroll
    for (int ic = 0; ic < 16; ic++) {
      float x[9];
#pragma unroll
      for (int dr = 0; dr < 3; dr++)
#pragma unroll
        for (int dc = 0; dc < 3; dc++)
          x[dr * 3 + dc] = lds[(ic * 4 + orow2 + dr) * 66 + w + dc];
      const float* wb = wt + (size_t)(og * 8 + oh * 4) * 576 + (icc * 16 + ic) * 9;
#pragma unroll
      for (int o = 0; o < 4; o++) {
        const float* wp = wb + o * 576;
#pragma unroll
        for (int j = 0; j < 9; j++) acc[o] += wp[j] * x[j];
      }
    }
  }
  int orow = rt * 2 + orow2;
#pragma unroll
  for (int o = 0; o < 4; o++) {
    int oc = og * 8 + oh * 4 + o;
    float rz = acc[o] + bias[oc];
    if (RELU) rz = fmaxf(rz, 0.f);
    out[((size_t)q * 64 + oc) * HW + orow * 64 + w] = rz;
  }
}

// ---------------- small 3x3 conv (1 or 2 oc), proven round-1 version ----------
template <int OC, int OCPB, bool RELU>
__global__ __launch_bounds__(256) void k_conv3(const float* __restrict__ in,
                                               const float* __restrict__ wt,
                                               const float* __restrict__ bias,
                                               float* __restrict__ out) {
  constexpr int NOG = OC / OCPB;
  __shared__ float lds[16 * 6 * 66];
  int b = blockIdx.x;
  int og = b % NOG;
  int rt = (b / NOG) & 15;
  int q = b / (NOG * 16);
  int t = threadIdx.x;
  int w = t & 63, wr = t >> 6;
  float acc[OCPB];
#pragma unroll
  for (int o = 0; o < OCPB; o++) acc[o] = 0.f;
  const float* inq = in + (size_t)q * 64 * HW;
  for (int icc = 0; icc < 4; icc++) {
    __syncthreads();
    for (int e = t; e < 16 * 6 * 66; e += 256) {
      int cc = e % 66;
      int tmp = e / 66;
      int r = tmp % 6, ch = tmp / 6;
      int col = cc - 1;
      int grow = rt * 4 + r - 1;
      float val = 0.f;
      if (col >= 0 && col < 64 && grow >= 0 && grow < 64)
        val = inq[(icc * 16 + ch) * HW + grow * 64 + col];
      lds[e] = val;
    }
    __syncthreads();
#pragma unroll 4
    for (int ic = 0; ic < 16; ic++) {
      float x00 = lds[(ic * 6 + wr) * 66 + w];
      float x01 = lds[(ic * 6 + wr) * 66 + w + 1];
      float x02 = lds[(ic * 6 + wr) * 66 + w + 2];
      float x10 = lds[(ic * 6 + wr + 1) * 66 + w];
      float x11 = lds[(ic * 6 + wr + 1) * 66 + w + 1];
      float x12 = lds[(ic * 6 + wr + 1) * 66 + w + 2];
      float x20 = lds[(ic * 6 + wr + 2) * 66 + w];
      float x21 = lds[(ic * 6 + wr + 2) * 66 + w + 1];
      float x22 = lds[(ic * 6 + wr + 2) * 66 + w + 2];
      const float* wb = wt + (size_t)og * OCPB * 576 + (icc * 16 + ic) * 9;
#pragma unroll
      for (int o = 0; o < OCPB; o++) {
        const float* wp = wb + o * 576;
        acc[o] += wp[0] * x00 + wp[1] * x01 + wp[2] * x02 + wp[3] * x10 +
                  wp[4] * x11 + wp[5] * x12 + wp[6] * x20 + wp[7] * x21 +
                  wp[8] * x22;
      }
    }
  }
  int orow = rt * 4 + wr;
#pragma unroll
  for (int o = 0; o < OCPB; o++) {
    float r = acc[o] + bias[og * OCPB + o];
    if (RELU) r = fmaxf(r, 0.f);
    out[((size_t)q * OC + og * OCPB + o) * HW + orow * 64 + w] = r;
  }
}

// ---------------- final: argmax + pos/scl ----------------
__global__ __launch_bounds__(256) void k_final(const float* __restrict__ scores,
                                               const float* __restrict__ scales,
                                               const float* __restrict__ offsets,
                                               float* __restrict__ pos,
                                               float* __restrict__ sclo) {
  int q = blockIdx.x, t = threadIdx.x;
  float best = -3.4e38f;
  int bi = 1 << 30;
  for (int i = t; i < HW; i += 256) {
    float v = scores[q * HW + i];
    if (v > best) { best = v; bi = i; }
  }
  __shared__ float bv[256];
  __shared__ int bix[256];
  bv[t] = best;
  bix[t] = bi;
  __syncthreads();
  for (int s = 128; s > 0; s >>= 1) {
    if (t < s) {
      if (bv[t + s] > bv[t] || (bv[t + s] == bv[t] && bix[t + s] < bix[t])) {
        bv[t] = bv[t + s];
        bix[t] = bix[t + s];
      }
    }
    __syncthreads();
  }
  if (t == 0) {
    int sid = bix[0];
    int sy = sid >> 6, sx = sid & 63;
    float o0 = offsets[(q * 2 + 0) * HW + sid];
    float o1 = offsets[(q * 2 + 1) * HW + sid];
    pos[q * 2 + 0] = ((float)sx + o0 + 0.5f) * 8.f - 0.5f;
    pos[q * 2 + 1] = ((float)sy + o1 + 0.5f) * 8.f - 0.5f;
    sclo[q] = exp2f(scales[q * HW + sid]);
  }
}

extern "C" void kernel_launch(void* const* d_in, const int* in_sizes, int n_in,
                              void* d_out, int out_size, void* d_ws, size_t ws_size,
                              hipStream_t stream) {
  const float* corr = (const float*)d_in[0];
  const float* w1s = (const float*)d_in[1];
  const float* b1s = (const float*)d_in[2];
  const float* w2s = (const float*)d_in[3];
  const float* b2s = (const float*)d_in[4];
  const float* w1c = (const float*)d_in[5];
  const float* b1c = (const float*)d_in[6];
  const float* w2c = (const float*)d_in[7];
  const float* b2c = (const float*)d_in[8];

  float* out = (float*)d_out;
  float* pos = out;                   // (4,2)
  float* sclo = out + 8;              // (4,)
  float* scores = out + 12;           // (4,1,64,64)
  float* scales = out + 12 + 16384;   // (4,1,64,64)
  float* offsets = out + 12 + 32768;  // (4,2,64,64)

  char* ws = (char*)d_ws;
  float* st_scl = (float*)(ws + 0);         // 9216 f
  float* st_shf = (float*)(ws + 36864);     // 9216 f
  int* topidx = (int*)(ws + 73728);         // 65536 int4 = 1 MB
  float* rs = (float*)(ws + 1122304);       // 8.39 MB
  float* xs = (float*)(ws + 9510912);       // 4.19 MB
  float* xc = (float*)(ws + 13705216);      // 4.19 MB
  float* t1 = (float*)(ws + 17899520);      // 4.19 MB
  float* t2 = (float*)(ws + 22093824);      // 4.19 MB (total 26.3 MB)

  k_stats<<<9216, 256, 0, stream>>>(corr, st_scl, st_shf);
  k_refscore<<<2048, 256, 0, stream>>>(corr, st_scl, st_shf, rs);
  k_topk<<<256, 256, 0, stream>>>(rs, topidx);
  k_mlp<<<512, 128, 0, stream>>>(corr, st_scl, st_shf, topidx, w1s, b1s, w2s,
                                 b2s, w1c, b1c, w2c, b2c, xs, xc);
  // scale head -> scales
  k_conv64<true><<<1024, 256, 0, stream>>>(xs, (const float*)d_in[9], (const float*)d_in[10], t1);
  k_conv64<true><<<1024, 256, 0, stream>>>(t1, (const float*)d_in[11], (const float*)d_in[12], t2);
  k_conv3<1, 1, false><<<64, 256, 0, stream>>>(t2, (const float*)d_in[13], (const float*)d_in[14], scales);
  // offset head -> offsets
  k_conv64<true><<<1024, 256, 0, stream>>>(xc, (const float*)d_in[15], (const float*)d_in[16], t1);
  k_conv64<true><<<1024, 256, 0, stream>>>(t1, (const float*)d_in[17], (const float*)d_in[18], t2);
  k_conv3<2, 2, false><<<64, 256, 0, stream>>>(t2, (const float*)d_in[19], (const float*)d_in[20], offsets);
  // score head -> scores
  k_conv64<true><<<1024, 256, 0, stream>>>(xc, (const float*)d_in[21], (const float*)d_in[22], t1);
  k_conv64<true><<<1024, 256, 0, stream>>>(t1, (const float*)d_in[23], (const float*)d_in[24], t2);
  k_conv3<1, 1, false><<<64, 256, 0, stream>>>(t2, (const float*)d_in[25], (const float*)d_in[26], scores);

  k_final<<<4, 256, 0, stream>>>(scores, scales, offsets, pos, sclo);
}

// Round 3
// 983.577 us; speedup vs baseline: 1.1808x; 1.0929x over previous
//
#include <hip/hip_runtime.h>

#define HW 4096

// ---------------- kernel A: per-(q,r,ns,c) instance-norm stats ----------------
__global__ __launch_bounds__(256) void k_stats(const float* __restrict__ corr,
                                               float* __restrict__ scl,
                                               float* __restrict__ shf) {
  int g = blockIdx.x;  // 0..9215  linear over [q][r][ns][c]
  const float4* p = (const float4*)(corr + (size_t)g * HW);
  int t = threadIdx.x;
  float s = 0.f, s2 = 0.f;
#pragma unroll
  for (int i = 0; i < 4; i++) {
    float4 v = p[t + i * 256];
    s += v.x + v.y + v.z + v.w;
    s2 += v.x * v.x + v.y * v.y + v.z * v.z + v.w * v.w;
  }
#pragma unroll
  for (int o = 32; o > 0; o >>= 1) {
    s += __shfl_down(s, o, 64);
    s2 += __shfl_down(s2, o, 64);
  }
  __shared__ float ls[4], ls2[4];
  int wid = t >> 6;
  if ((t & 63) == 0) { ls[wid] = s; ls2[wid] = s2; }
  __syncthreads();
  if (t == 0) {
    float S = ls[0] + ls[1] + ls[2] + ls[3];
    float S2 = ls2[0] + ls2[1] + ls2[2] + ls2[3];
    float m = S * (1.f / HW);
    float var = S2 * (1.f / HW) - m * m;
    float r = rsqrtf(var + 1e-5f);
    scl[g] = r;
    shf[g] = -m * r;
  }
}

// ---------------- kernel B: ref_score = mean_c corr_n -> rs[(q*32+r)*4+ns][px]
__global__ __launch_bounds__(256) void k_refscore(const float* __restrict__ corr,
                                                  const float* __restrict__ scl,
                                                  const float* __restrict__ shf,
                                                  float* __restrict__ rs) {
  int b = blockIdx.x;     // 2048
  int grp = b >> 2;       // 0..511
  int i4 = (b & 3) * 256 + threadIdx.x;  // float4 index 0..1023
  const float* base = corr + (size_t)grp * 18 * HW;
  float4 acc = make_float4(0.f, 0.f, 0.f, 0.f);
  float sh = 0.f;
#pragma unroll
  for (int c = 0; c < 18; c++) {
    float s = scl[grp * 18 + c];
    sh += shf[grp * 18 + c];
    float4 v = ((const float4*)(base + c * HW))[i4];
    acc.x += v.x * s; acc.y += v.y * s; acc.z += v.z * s; acc.w += v.w * s;
  }
  const float inv = 1.f / 18.f;
  float4 o;
  o.x = (acc.x + sh) * inv; o.y = (acc.y + sh) * inv;
  o.z = (acc.z + sh) * inv; o.w = (acc.w + sh) * inv;
  ((float4*)(rs + (size_t)grp * HW))[i4] = o;
}

// ---------------- kernel C: top-4 of 32, LDS-staged ----------------
__global__ __launch_bounds__(256) void k_topk(const float* __restrict__ rs,
                                              int* __restrict__ topidx) {
  __shared__ float st[32 * 256];  // 32 KB
  int b = blockIdx.x;             // 256 = q*4ns*16pxc
  int pxc = b & 15;
  int ns = (b >> 4) & 3;
  int q = b >> 6;
  int t = threadIdx.x;
  int pxb = pxc * 256;
#pragma unroll 8
  for (int r = 0; r < 32; r++)
    st[r * 256 + t] = rs[((q * 32 + r) * 4 + ns) * HW + pxb + t];
  __syncthreads();
  float v[32];
#pragma unroll
  for (int r = 0; r < 32; r++) v[r] = st[r * 256 + t];
  unsigned mask = 0;
  int sel[4];
#pragma unroll
  for (int k = 0; k < 4; k++) {
    float best = -3.4e38f;
    int bi = 0;
#pragma unroll
    for (int r = 0; r < 32; r++) {
      bool take = (!(mask & (1u << r))) && (v[r] > best);
      best = take ? v[r] : best;
      bi = take ? r : bi;
    }
    sel[k] = bi;
    mask |= (1u << bi);
  }
  ((int4*)topidx)[(q * 4 + ns) * HW + pxb + t] =
      make_int4(sel[0], sel[1], sel[2], sel[3]);
}

// -------- kernel D1: high-occupancy streaming gather+norm -> vbuf ----------
// grid 4608 = q(4) x pxc(16) x ns(4) x c(18); 256 thr, 1 px each.
// Streams all 32 r-rows coalesced, cndmask-selects the top-4, normalizes.
__global__ __launch_bounds__(256) void k_gather(const float* __restrict__ corr,
                                                const float* __restrict__ scl,
                                                const float* __restrict__ shf,
                                                const int* __restrict__ topidx,
                                                float* __restrict__ vbuf) {
  __shared__ float ls[32], lsh[32];
  int b = blockIdx.x;
  int c = b % 18;
  int rest = b / 18;
  int ns = rest & 3;
  int pxc = (rest >> 2) & 15;
  int q = rest >> 6;
  int t = threadIdx.x;
  int px = pxc * 256 + t;

  if (t < 32) {
    int g = q * 2304 + t * 72 + ns * 18 + c;
    ls[t] = scl[g];
    lsh[t] = shf[g];
  }
  int4 ti = ((const int4*)topidx)[(q * 4 + ns) * HW + px];
  int rk0 = ti.x, rk1 = ti.y, rk2 = ti.z, rk3 = ti.w;
  __syncthreads();

  const float* base = corr + (size_t)(((q * 32) * 4 + ns) * 18 + c) * HW + px;
  float v0 = 0.f, v1 = 0.f, v2 = 0.f, v3 = 0.f;
#pragma unroll
  for (int r = 0; r < 32; r++) {
    float x = base[(size_t)r * 72 * HW];
    v0 = (rk0 == r) ? x : v0;
    v1 = (rk1 == r) ? x : v1;
    v2 = (rk2 == r) ? x : v2;
    v3 = (rk3 == r) ? x : v3;
  }
  v0 = v0 * ls[rk0] + lsh[rk0];
  v1 = v1 * ls[rk1] + lsh[rk1];
  v2 = v2 * ls[rk2] + lsh[rk2];
  v3 = v3 * ls[rk3] + lsh[rk3];
  size_t ob = (size_t)((q * 4 + ns) * 72 + c) * HW + px;
  vbuf[ob] = v0;
  vbuf[ob + 18 * HW] = v1;
  vbuf[ob + 36 * HW] = v2;
  vbuf[ob + 54 * HW] = v3;
}

// -------- kernel D2: both 2-layer 1x1x1 MLPs + NS-max from compact vbuf ----
__global__ __launch_bounds__(128) void k_mlp2(
    const float* __restrict__ vbuf,
    const float* __restrict__ w1s, const float* __restrict__ b1s,
    const float* __restrict__ w2s, const float* __restrict__ b2s,
    const float* __restrict__ w1c, const float* __restrict__ b1c,
    const float* __restrict__ w2c, const float* __restrict__ b2c,
    float* __restrict__ xs, float* __restrict__ xc) {
  __shared__ float hs[64 * 128];   // 32 KB
  __shared__ float rbuf[8 * 128];  // 4 KB
  int b = blockIdx.x;  // 512
  int q = b >> 7;
  int pxbase = (b & 127) * 32;
  int tid = threadIdx.x;
  int ns = tid >> 5;
  int lane = tid & 31;
  int px = pxbase + lane;

  float v[72];
  const float* vb = vbuf + (size_t)((q * 4 + ns) * 72) * HW + px;
#pragma unroll
  for (int j = 0; j < 72; j++) v[j] = vb[j * HW];

  float xsc[12];
#pragma unroll
  for (int k = 0; k < 4; k++)
#pragma unroll
    for (int l = 0; l < 3; l++) {
      float s = 0.f;
#pragma unroll
      for (int j = 0; j < 6; j++) s += v[k * 18 + l * 6 + j];
      xsc[k * 3 + l] = s * (1.f / 6.f);
    }
  // scale path layer 1 (o-loop uniform -> scalar weight loads)
  for (int o = 0; o < 64; o++) {
    float t = b1s[o];
#pragma unroll
    for (int c = 0; c < 72; c++) t += w1s[o * 72 + c] * v[c];
    hs[o * 128 + tid] = fmaxf(t, 0.f);
  }
  __syncthreads();
  // scale path layer 2 + ns-max
  for (int og = 0; og < 8; og++) {
    float t[8];
#pragma unroll
    for (int j = 0; j < 8; j++) t[j] = b2s[og * 8 + j];
#pragma unroll 8
    for (int c = 0; c < 64; c++) {
      float x = hs[c * 128 + tid];
#pragma unroll
      for (int j = 0; j < 8; j++) t[j] += w2s[(og * 8 + j) * 64 + c] * x;
    }
#pragma unroll
    for (int j = 0; j < 8; j++) rbuf[j * 128 + tid] = t[j];
    __syncthreads();
#pragma unroll
    for (int pass = 0; pass < 2; pass++) {
      int j2 = (tid >> 5) + pass * 4;
      float m = rbuf[j2 * 128 + lane];
#pragma unroll
      for (int n2 = 1; n2 < 4; n2++) m = fmaxf(m, rbuf[j2 * 128 + n2 * 32 + lane]);
      xs[(q * 64 + og * 8 + j2) * HW + pxbase + lane] = m;
    }
    __syncthreads();
  }
  // score path layer 1
  for (int o = 0; o < 64; o++) {
    float t = b1c[o];
#pragma unroll
    for (int c = 0; c < 12; c++) t += w1c[o * 12 + c] * xsc[c];
    hs[o * 128 + tid] = fmaxf(t, 0.f);
  }
  __syncthreads();
  // score path layer 2 + ns-max
  for (int og = 0; og < 8; og++) {
    float t[8];
#pragma unroll
    for (int j = 0; j < 8; j++) t[j] = b2c[og * 8 + j];
#pragma unroll 8
    for (int c = 0; c < 64; c++) {
      float x = hs[c * 128 + tid];
#pragma unroll
      for (int j = 0; j < 8; j++) t[j] += w2c[(og * 8 + j) * 64 + c] * x;
    }
#pragma unroll
    for (int j = 0; j < 8; j++) rbuf[j * 128 + tid] = t[j];
    __syncthreads();
#pragma unroll
    for (int pass = 0; pass < 2; pass++) {
      int j2 = (tid >> 5) + pass * 4;
      float m = rbuf[j2 * 128 + lane];
#pragma unroll
      for (int n2 = 1; n2 < 4; n2++) m = fmaxf(m, rbuf[j2 * 128 + n2 * 32 + lane]);
      xc[(q * 64 + og * 8 + j2) * HW + pxbase + lane] = m;
    }
    __syncthreads();
  }
}

// ---- big 3x3 conv, 64ic->64oc: 8 oc/thread, UNIFORM weight addr (s_load) ----
template <bool RELU>
__global__ __launch_bounds__(256) void k_conv64(const float* __restrict__ in,
                                                const float* __restrict__ wt,
                                                const float* __restrict__ bias,
                                                float* __restrict__ out) {
  __shared__ float tile[16 * 6 * 66];  // 25.3 KB
  int b = blockIdx.x;                  // 512 = q(4) x rt(16) x og(8)
  int og = b & 7;
  int rt = (b >> 3) & 15;
  int q = b >> 7;
  int t = threadIdx.x;
  int w = t & 63;
  int wr = t >> 6;  // 0..3: output row in tile; uniform per wave
  float acc[8] = {0.f, 0.f, 0.f, 0.f, 0.f, 0.f, 0.f, 0.f};
  if (t < 96) { tile[t * 66] = 0.f; tile[t * 66 + 65] = 0.f; }
  const float* inq = in + (size_t)q * 64 * HW;
  for (int icc = 0; icc < 4; icc++) {
    __syncthreads();
#pragma unroll
    for (int p = 0; p < 24; p++) {
      int idx = p * 4 + wr;          // (ch*6 + r), 0..95
      int r = idx % 6;
      int ch = idx / 6;
      int grow = rt * 4 + r - 1;
      float val = 0.f;
      if (grow >= 0 && grow < 64)
        val = inq[(size_t)(icc * 16 + ch) * HW + grow * 64 + w];
      tile[idx * 66 + 1 + w] = val;
    }
    __syncthreads();
#pragma unroll 2
    for (int ic = 0; ic < 16; ic++) {
      float x[9];
#pragma unroll
      for (int dr = 0; dr < 3; dr++)
#pragma unroll
        for (int dc = 0; dc < 3; dc++)
          x[dr * 3 + dc] = tile[(ic * 6 + wr + dr) * 66 + w + dc];
      // weight address depends only on blockIdx & loop vars -> scalar loads
      const float* wb = wt + (size_t)og * 8 * 576 + (icc * 16 + ic) * 9;
#pragma unroll
      for (int o = 0; o < 8; o++) {
        const float* wp = wb + o * 576;
#pragma unroll
        for (int j = 0; j < 9; j++) acc[o] += wp[j] * x[j];
      }
    }
  }
  int orow = rt * 4 + wr;
#pragma unroll
  for (int o = 0; o < 8; o++) {
    float rz = acc[o] + bias[og * 8 + o];
    if (RELU) rz = fmaxf(rz, 0.f);
    out[((size_t)q * 64 + og * 8 + o) * HW + orow * 64 + w] = rz;
  }
}

// ---- small 3x3 conv (OC=1,2): 2-row tiles, ic split across thread halves ----
template <int OC>
__global__ __launch_bounds__(256) void k_convS(const float* __restrict__ in,
                                               const float* __restrict__ wt,
                                               const float* __restrict__ bias,
                                               float* __restrict__ out) {
  __shared__ float tile[32 * 4 * 66];      // 33.8 KB
  __shared__ float red[2 * 2 * OC * 64];   // ih x row2 x oc x col
  int b = blockIdx.x;  // 128 = q(4) x rt(32)
  int rt = b & 31;
  int q = b >> 5;
  int t = threadIdx.x;
  int w = t & 63;
  int sub = t >> 6;      // 0..3
  int row2 = sub & 1;    // output row within 2-row tile
  int ih = sub >> 1;     // ic half
  float acc[OC];
#pragma unroll
  for (int o = 0; o < OC; o++) acc[o] = 0.f;
  if (t < 128) { tile[t * 66] = 0.f; tile[t * 66 + 65] = 0.f; }
  const float* inq = in + (size_t)q * 64 * HW;
  for (int icc = 0; icc < 2; icc++) {
    __syncthreads();
#pragma unroll
    for (int p = 0; p < 32; p++) {
      int idx = p * 4 + sub;  // ch*4 + r, 0..127
      int r = idx & 3;
      int ch = idx >> 2;
      int grow = rt * 2 + r - 1;
      float val = 0.f;
      if (grow >= 0 && grow < 64)
        val = inq[(size_t)(icc * 32 + ch) * HW + grow * 64 + w];
      tile[idx * 66 + 1 + w] = val;
    }
    __syncthreads();
#pragma unroll 4
    for (int i = 0; i < 16; i++) {
      int ic = ih * 16 + i;
      float x[9];
#pragma unroll
      for (int dr = 0; dr < 3; dr++)
#pragma unroll
        for (int dc = 0; dc < 3; dc++)
          x[dr * 3 + dc] = tile[(ic * 4 + row2 + dr) * 66 + w + dc];
      const float* wb = wt + (size_t)(icc * 32 + ic) * 9;
#pragma unroll
      for (int o = 0; o < OC; o++) {
        const float* wp = wb + o * 576;
#pragma unroll
        for (int j = 0; j < 9; j++) acc[o] += wp[j] * x[j];
      }
    }
  }
#pragma unroll
  for (int o = 0; o < OC; o++) red[((ih * 2 + row2) * OC + o) * 64 + w] = acc[o];
  __syncthreads();
  if (sub < 2) {
    int orow = rt * 2 + sub;
#pragma unroll
    for (int o = 0; o < OC; o++) {
      float s = red[((0 * 2 + sub) * OC + o) * 64 + w] +
                red[((1 * 2 + sub) * OC + o) * 64 + w] + bias[o];
      out[((size_t)q * OC + o) * HW + orow * 64 + w] = s;
    }
  }
}

// ---------------- final: argmax + pos/scl ----------------
__global__ __launch_bounds__(256) void k_final(const float* __restrict__ scores,
                                               const float* __restrict__ scales,
                                               const float* __restrict__ offsets,
                                               float* __restrict__ pos,
                                               float* __restrict__ sclo) {
  int q = blockIdx.x, t = threadIdx.x;
  float best = -3.4e38f;
  int bi = 1 << 30;
  for (int i = t; i < HW; i += 256) {
    float v = scores[q * HW + i];
    if (v > best) { best = v; bi = i; }
  }
  __shared__ float bv[256];
  __shared__ int bix[256];
  bv[t] = best;
  bix[t] = bi;
  __syncthreads();
  for (int s = 128; s > 0; s >>= 1) {
    if (t < s) {
      if (bv[t + s] > bv[t] || (bv[t + s] == bv[t] && bix[t + s] < bix[t])) {
        bv[t] = bv[t + s];
        bix[t] = bix[t + s];
      }
    }
    __syncthreads();
  }
  if (t == 0) {
    int sid = bix[0];
    int sy = sid >> 6, sx = sid & 63;
    float o0 = offsets[(q * 2 + 0) * HW + sid];
    float o1 = offsets[(q * 2 + 1) * HW + sid];
    pos[q * 2 + 0] = ((float)sx + o0 + 0.5f) * 8.f - 0.5f;
    pos[q * 2 + 1] = ((float)sy + o1 + 0.5f) * 8.f - 0.5f;
    sclo[q] = exp2f(scales[q * HW + sid]);
  }
}

extern "C" void kernel_launch(void* const* d_in, const int* in_sizes, int n_in,
                              void* d_out, int out_size, void* d_ws, size_t ws_size,
                              hipStream_t stream) {
  const float* corr = (const float*)d_in[0];
  const float* w1s = (const float*)d_in[1];
  const float* b1s = (const float*)d_in[2];
  const float* w2s = (const float*)d_in[3];
  const float* b2s = (const float*)d_in[4];
  const float* w1c = (const float*)d_in[5];
  const float* b1c = (const float*)d_in[6];
  const float* w2c = (const float*)d_in[7];
  const float* b2c = (const float*)d_in[8];

  float* out = (float*)d_out;
  float* pos = out;                   // (4,2)
  float* sclo = out + 8;              // (4,)
  float* scores = out + 12;           // (4,1,64,64)
  float* scales = out + 12 + 16384;   // (4,1,64,64)
  float* offsets = out + 12 + 32768;  // (4,2,64,64)

  char* ws = (char*)d_ws;
  float* st_scl = (float*)(ws + 0);         // 9216 f = 36 KB
  float* st_shf = (float*)(ws + 36864);     // 36 KB
  int* topidx = (int*)(ws + 73728);         // 1 MB
  float* rs = (float*)(ws + 1122304);       // 8.39 MB (dead after k_topk)
  float* vbuf = rs;                         // 18.87 MB, overlaps rs (ok)
  float* xs = (float*)(ws + 20439040);      // 4.19 MB
  float* xc = (float*)(ws + 24633344);      // 4.19 MB
  float* t1 = (float*)(ws + 28827648);      // 4.19 MB
  float* t2 = (float*)(ws + 33021952);      // 4.19 MB (total 37.2 MB)

  k_stats<<<9216, 256, 0, stream>>>(corr, st_scl, st_shf);
  k_refscore<<<2048, 256, 0, stream>>>(corr, st_scl, st_shf, rs);
  k_topk<<<256, 256, 0, stream>>>(rs, topidx);
  k_gather<<<4608, 256, 0, stream>>>(corr, st_scl, st_shf, topidx, vbuf);
  k_mlp2<<<512, 128, 0, stream>>>(vbuf, w1s, b1s, w2s, b2s, w1c, b1c, w2c, b2c,
                                  xs, xc);
  // scale head -> scales
  k_conv64<true><<<512, 256, 0, stream>>>(xs, (const float*)d_in[9], (const float*)d_in[10], t1);
  k_conv64<true><<<512, 256, 0, stream>>>(t1, (const float*)d_in[11], (const float*)d_in[12], t2);
  k_convS<1><<<128, 256, 0, stream>>>(t2, (const float*)d_in[13], (const float*)d_in[14], scales);
  // offset head -> offsets
  k_conv64<true><<<512, 256, 0, stream>>>(xc, (const float*)d_in[15], (const float*)d_in[16], t1);
  k_conv64<true><<<512, 256, 0, stream>>>(t1, (const float*)d_in[17], (const float*)d_in[18], t2);
  k_convS<2><<<128, 256, 0, stream>>>(t2, (const float*)d_in[19], (const float*)d_in[20], offsets);
  // score head -> scores
  k_conv64<true><<<512, 256, 0, stream>>>(xc, (const float*)d_in[21], (const float*)d_in[22], t1);
  k_conv64<true><<<512, 256, 0, stream>>>(t1, (const float*)d_in[23], (const float*)d_in[24], t2);
  k_convS<1><<<128, 256, 0, stream>>>(t2, (const float*)d_in[25], (const float*)d_in[26], scores);

  k_final<<<4, 256, 0, stream>>>(scores, scales, offsets, pos, sclo);
}